// Round 6
// baseline (1059.441 us; speedup 1.0000x reference)
//
#include <hip/hip_runtime.h>
#include <hip/hip_bf16.h>
#include <math.h>

// Problem constants
static constexpr int  Bn = 8, Dn = 1024, Ln = 2048;
static constexpr long DL  = (long)Dn * Ln;
static constexpr long DDm = (long)Dn * Dn;
static constexpr long LLm = (long)Ln * Ln;
static constexpr float P_EXP = 1.01005016708416805754f; // exp(0.01)
static constexpr float PI_F  = 3.14159265358979323846f;

using bf = __hip_bfloat16;
typedef short s16x8 __attribute__((ext_vector_type(8)));   // 8 bf16 = 4 VGPRs (MFMA A/B frag)
typedef float f32x4 __attribute__((ext_vector_type(4)));   // MFMA C/D frag

#define GPTR(x) ((const __attribute__((address_space(1))) void*)(x))
#define LPTR(x) ((__attribute__((address_space(3))) void*)(x))

enum { EPI_BIAS = 0, EPI_PLAIN = 1, EPI_CAUCHY = 2, EPI_RESID = 3, EPI_BIASM = 4, EPI_CAUCHYB = 5 };

// bf16 RNE pack (finite values only)
static __device__ inline unsigned short f2bf_rne(float f)
{
    union { float f; unsigned u; } uf; uf.f = f;
    unsigned r = uf.u + 0x7fff + ((uf.u >> 16) & 1);
    return (unsigned short)(r >> 16);
}
static __device__ inline float bf2f(unsigned short s)
{
    union { unsigned u; float f; } uf; uf.u = ((unsigned)s) << 16;
    return uf.f;
}

struct P4 { const float* p[4]; };

// ---------------------------------------------------------------------------
// NT bf16 MFMA GEMM: C[b,m,n] = sum_k A[b,m,k] * Bt[b,n,k]   (both k-contig)
// 128x128 tile, BK=32, 256 threads (4 waves, 2x2 of 64x64 wave tiles),
// global_load_lds width-16 staging, swizzled LDS k-chunks.
// launch_bounds(256,3): ~170 reg/wave budget (m97 config: 3 blocks/CU,
// ~100 arch VGPR + 64 AGPR acc). (256,4) gave only 64 arch VGPRs -> VALU
// recompute thrash (VALUBusy 68% at MfmaUtil 11%, R5 counters).
// ---------------------------------------------------------------------------
template<int EPI>
__global__ __launch_bounds__(256, 3)
void gemm_nt(const short* __restrict__ A, long sAb, int ldA,
             const short* __restrict__ Bt, long sBb, int ldB,
             void* __restrict__ Cv, long sCb, int ldC,
             const float* __restrict__ bias,
             const float* __restrict__ rowN, const float* __restrict__ colN,
             const float* __restrict__ resid, long sRb,
             int M, int N, int K)
{
    __shared__ short As[128 * 32];   // row-major, 32 bf16 per row, k-chunk swizzled
    __shared__ short Bs[128 * 32];

    const int tid  = threadIdx.x;
    const int lane = tid & 63;
    const int w    = tid >> 6;           // wave 0..3
    const int wm   = w >> 1, wn = w & 1; // 2x2 wave grid
    const int m0   = blockIdx.y * 128;
    const int n0   = blockIdx.x * 128;
    const int bz   = blockIdx.z;

    const int srow = lane >> 2;                                  // 0..15 row within 16-row chunk
    const int kc   = ((lane & 3) + 4 - ((lane >> 3) & 3)) & 3;   // swizzled global k-chunk
    const int quad = lane >> 4;
    const int l15  = lane & 15;

    // LDS read offsets (shorts) for the 4 A / 4 B fragments
    int aoff[4], boff[4];
    #pragma unroll
    for (int i = 0; i < 4; ++i) {
        int rA = wm * 64 + i * 16 + l15;
        aoff[i] = rA * 32 + (((quad + (rA >> 1)) & 3) << 3);
        int rB = wn * 64 + i * 16 + l15;
        boff[i] = rB * 32 + (((quad + (rB >> 1)) & 3) << 3);
    }

    // staging: wave w owns 1KB chunks {2w, 2w+1} of both A and B tiles
    const int  ca0 = 2 * w;
    const short* pA0 = A  + (long)bz * sAb + (long)(m0 + ca0 * 16 + srow)       * ldA + kc * 8;
    const short* pA1 = A  + (long)bz * sAb + (long)(m0 + (ca0 + 1) * 16 + srow) * ldA + kc * 8;
    const short* pB0 = Bt + (long)bz * sBb + (long)(n0 + ca0 * 16 + srow)       * ldB + kc * 8;
    const short* pB1 = Bt + (long)bz * sBb + (long)(n0 + (ca0 + 1) * 16 + srow) * ldB + kc * 8;
    short* lA0 = As + ca0 * 512;
    short* lA1 = As + ca0 * 512 + 512;
    short* lB0 = Bs + ca0 * 512;
    short* lB1 = Bs + ca0 * 512 + 512;

    f32x4 acc[4][4] = {};

    for (int k0 = 0; k0 < K; k0 += 32) {
        __builtin_amdgcn_global_load_lds(GPTR(pA0), LPTR(lA0), 16, 0, 0);
        __builtin_amdgcn_global_load_lds(GPTR(pA1), LPTR(lA1), 16, 0, 0);
        __builtin_amdgcn_global_load_lds(GPTR(pB0), LPTR(lB0), 16, 0, 0);
        __builtin_amdgcn_global_load_lds(GPTR(pB1), LPTR(lB1), 16, 0, 0);
        pA0 += 32; pA1 += 32; pB0 += 32; pB1 += 32;
        __syncthreads();

        s16x8 af[4], bfr[4];
        #pragma unroll
        for (int i = 0; i < 4; ++i) af[i]  = *(const s16x8*)(As + aoff[i]);
        #pragma unroll
        for (int j = 0; j < 4; ++j) bfr[j] = *(const s16x8*)(Bs + boff[j]);
        #pragma unroll
        for (int i = 0; i < 4; ++i)
            #pragma unroll
            for (int j = 0; j < 4; ++j)
                acc[i][j] = __builtin_amdgcn_mfma_f32_16x16x32_bf16(af[i], bfr[j], acc[i][j], 0, 0, 0);
        __syncthreads();
    }

    // Epilogue. C/D layout: col = lane&15, row = quad*4 + r within each 16x16.
    if constexpr (EPI == EPI_BIAS || EPI == EPI_PLAIN || EPI == EPI_BIASM) {
        bf* C = (bf*)Cv + (long)bz * sCb;
        #pragma unroll
        for (int j = 0; j < 4; ++j) {
            int n = n0 + wn * 64 + j * 16 + l15;
            float bv = (EPI == EPI_BIAS) ? bias[n] : 0.f;
            #pragma unroll
            for (int i = 0; i < 4; ++i) {
                int mb = m0 + wm * 64 + i * 16 + quad * 4;
                #pragma unroll
                for (int r = 0; r < 4; ++r) {
                    float bm = (EPI == EPI_BIASM) ? bias[mb + r] : bv;
                    C[(long)(mb + r) * ldC + n] = __float2bfloat16(acc[i][j][r] + bm);
                }
            }
        }
    } else if constexpr (EPI == EPI_CAUCHY || EPI == EPI_CAUCHYB) {
        const float* rN = rowN + (long)bz * M;
        const float* cN = colN + (long)bz * N;
        #pragma unroll
        for (int j = 0; j < 4; ++j) {
            int n = n0 + wn * 64 + j * 16 + l15;
            float cn = cN[n];
            #pragma unroll
            for (int i = 0; i < 4; ++i) {
                int mb = m0 + wm * 64 + i * 16 + quad * 4;
                #pragma unroll
                for (int r = 0; r < 4; ++r) {
                    int m = mb + r;
                    float g = acc[i][j][r];
                    float ratio = (g * g) / (rN[m] * cn);
                    float o = __powf(ratio, P_EXP) - ((m == n) ? 1.f : 0.f);
                    float v = fmaxf(0.5f - 0.5f * __cosf(PI_F * o), 0.f);
                    if constexpr (EPI == EPI_CAUCHY)
                        ((float*)Cv + (long)bz * sCb)[(long)m * ldC + n] = v;
                    else
                        ((unsigned short*)Cv + (long)bz * sCb)[(long)m * ldC + n] = f2bf_rne(v);
                }
            }
        }
    } else { // EPI_RESID
        float* C = (float*)Cv + (long)bz * sCb;
        const float* Rs = resid + (long)bz * sRb;
        #pragma unroll
        for (int j = 0; j < 4; ++j) {
            int n = n0 + wn * 64 + j * 16 + l15;
            #pragma unroll
            for (int i = 0; i < 4; ++i) {
                int mb = m0 + wm * 64 + i * 16 + quad * 4;
                #pragma unroll
                for (int r = 0; r < 4; ++r) {
                    int m = mb + r;
                    C[(long)m * ldC + n] = (acc[i][j][r] + Rs[(long)m * ldC + n]) * 0.5f;
                }
            }
        }
    }
}

// ---------------------------------------------------------------------------
// Transpose-cast: in (nb, R, C) [TI = float or bf16] -> out (nb, C, R) bf16.
// ---------------------------------------------------------------------------
template<typename TI>
__global__ __launch_bounds__(256)
void transpose_cast(const TI* __restrict__ in, bf* __restrict__ outp, int R, int C)
{
    __shared__ float tile[32][33];
    long base = (long)blockIdx.z * R * C;
    int r0 = blockIdx.y * 32, c0 = blockIdx.x * 32;
    int tx = threadIdx.x & 31, ty = threadIdx.x >> 5;
    #pragma unroll
    for (int i = 0; i < 4; ++i)
        tile[ty + 8 * i][tx] = (float)in[base + (long)(r0 + ty + 8 * i) * C + c0 + tx];
    __syncthreads();
    #pragma unroll
    for (int i = 0; i < 4; ++i)
        outp[base + (long)(c0 + ty + 8 * i) * R + r0 + tx] = __float2bfloat16(tile[tx][ty + 8 * i]);
}

// Batched weight cast: W1b4/W2b4[k] = bf16(Wk[layer*DDm]), layer in {1,2}
__global__ __launch_bounds__(256)
void cast_w12(P4 w, bf* __restrict__ w1b4, bf* __restrict__ w2b4)
{
    long i = (long)blockIdx.x * 256 + threadIdx.x;   // over DDm/4
    int layer = blockIdx.y, k = blockIdx.z;
    const float4* src = (const float4*)(w.p[k] + (long)(layer + 1) * DDm);
    ushort4* dst = (ushort4*)((layer ? w2b4 : w1b4) + (long)k * DDm);
    float4 v = src[i];
    ushort4 o; o.x = f2bf_rne(v.x); o.y = f2bf_rne(v.y); o.z = f2bf_rne(v.z); o.w = f2bf_rne(v.w);
    dst[i] = o;
}

// Batched W0 transpose-cast: w0t4[k] = bf16(Wk[0]^T)
__global__ __launch_bounds__(256)
void transpose_w0(P4 w, bf* __restrict__ w0t4)
{
    __shared__ float tile[32][33];
    int k = blockIdx.z;
    const float* in = w.p[k];
    bf* outp = w0t4 + (long)k * DDm;
    int r0 = blockIdx.y * 32, c0 = blockIdx.x * 32;
    int tx = threadIdx.x & 31, ty = threadIdx.x >> 5;
    #pragma unroll
    for (int i = 0; i < 4; ++i)
        tile[ty + 8 * i][tx] = in[(long)(r0 + ty + 8 * i) * Dn + c0 + tx];
    __syncthreads();
    #pragma unroll
    for (int i = 0; i < 4; ++i)
        outp[(long)(c0 + ty + 8 * i) * Dn + r0 + tx] = __float2bfloat16(tile[tx][ty + 8 * i]);
}

// Batched bias compose. stage 0: out4[k]=W1_k*b0_k+b1_k; stage 1: out4[k]=W2_k*vin4[k]+b2_k
__global__ __launch_bounds__(256)
void matvec4(P4 w, P4 b, const float* __restrict__ vin4, float* __restrict__ out4, int stage)
{
    int k = blockIdx.y, o = blockIdx.x;
    const float* W = w.p[k] + (long)(stage ? 2 : 1) * DDm + (long)o * Dn;
    const float* v = stage ? (vin4 + (long)k * Dn) : b.p[k];
    const float* c = b.p[k] + (long)(stage ? 2 : 1) * Dn;
    float s = 0.f;
    for (int i = threadIdx.x; i < Dn; i += 256) s += W[i] * v[i];
    __shared__ float red[256];
    red[threadIdx.x] = s; __syncthreads();
    for (int off = 128; off > 0; off >>= 1) {
        if (threadIdx.x < off) red[threadIdx.x] += red[threadIdx.x + off];
        __syncthreads();
    }
    if (threadIdx.x == 0) out4[(long)k * Dn + o] = red[0] + c[o];
}

// Strided row sum-of-squares (bf16 in, fp32 out), vectorized ushort4.
// row -> b = row / rpb, r = row % rpb; base = b*bstride + r*ld; ncols in {1024,2048}
__global__ __launch_bounds__(256)
void rowsumsq_s(const unsigned short* __restrict__ v, float* __restrict__ outp,
                int ncols, int ld, int rpb, long bstride)
{
    int row = blockIdx.x;
    int b = row / rpb, r = row % rpb;
    const unsigned short* p = v + (long)b * bstride + (long)r * ld;
    float s = 0.f;
    for (int c4 = threadIdx.x * 4; c4 < ncols; c4 += 1024) {
        ushort4 u = *(const ushort4*)(p + c4);
        float a0 = bf2f(u.x), a1 = bf2f(u.y), a2 = bf2f(u.z), a3 = bf2f(u.w);
        s += a0 * a0 + a1 * a1 + a2 * a2 + a3 * a3;
    }
    __shared__ float red[256];
    red[threadIdx.x] = s; __syncthreads();
    for (int off = 128; off > 0; off >>= 1) {
        if (threadIdx.x < off) red[threadIdx.x] += red[threadIdx.x + off];
        __syncthreads();
    }
    if (threadIdx.x == 0) outp[row] = red[0];
}

// ---------------------------------------------------------------------------
// Row softmax, fp32 in (rows x M contiguous) -> bf16 out (channel branch).
// ---------------------------------------------------------------------------
template<int M>
__global__ __launch_bounds__(256)
void softmax_row_bf16(const float* __restrict__ G, bf* __restrict__ outp)
{
    constexpr int NV = M / 1024;    // float4s per thread
    long row = blockIdx.x;
    const float4* p = (const float4*)(G + row * (long)M);
    ushort4* q = (ushort4*)(outp + row * (long)M);
    __shared__ float red[256];

    float4 v[NV];
    float lmax = -3.4e38f;
    #pragma unroll
    for (int k = 0; k < NV; ++k) {
        v[k] = p[threadIdx.x + 256 * k];
        lmax = fmaxf(lmax, fmaxf(fmaxf(v[k].x, v[k].y), fmaxf(v[k].z, v[k].w)));
    }
    red[threadIdx.x] = lmax; __syncthreads();
    for (int off = 128; off > 0; off >>= 1) {
        if (threadIdx.x < off) red[threadIdx.x] = fmaxf(red[threadIdx.x], red[threadIdx.x + off]);
        __syncthreads();
    }
    float mm = red[0]; __syncthreads();

    float s = 0.f;
    #pragma unroll
    for (int k = 0; k < NV; ++k) {
        v[k].x = __expf(v[k].x - mm); v[k].y = __expf(v[k].y - mm);
        v[k].z = __expf(v[k].z - mm); v[k].w = __expf(v[k].w - mm);
        s += (v[k].x + v[k].y) + (v[k].z + v[k].w);
    }
    red[threadIdx.x] = s; __syncthreads();
    for (int off = 128; off > 0; off >>= 1) {
        if (threadIdx.x < off) red[threadIdx.x] += red[threadIdx.x + off];
        __syncthreads();
    }
    float inv = 1.f / red[0];
    #pragma unroll
    for (int k = 0; k < NV; ++k) {
        ushort4 o;
        o.x = f2bf_rne(v[k].x * inv); o.y = f2bf_rne(v[k].y * inv);
        o.z = f2bf_rne(v[k].z * inv); o.w = f2bf_rne(v[k].w * inv);
        q[threadIdx.x + 256 * k] = o;
    }
}

// In-place row softmax on bf16, M = Ln (2048): 8 shorts/thread, one 16B ld/st.
__global__ __launch_bounds__(256)
void softmax_ip_bf16(unsigned short* __restrict__ G)
{
    long row = blockIdx.x;
    s16x8* p = (s16x8*)(G + row * (long)Ln);
    s16x8 raw = p[threadIdx.x];
    float v[8];
    #pragma unroll
    for (int j = 0; j < 8; ++j) v[j] = bf2f((unsigned short)raw[j]);

    __shared__ float red[256];
    float lmax = -3.4e38f;
    #pragma unroll
    for (int j = 0; j < 8; ++j) lmax = fmaxf(lmax, v[j]);
    red[threadIdx.x] = lmax; __syncthreads();
    for (int off = 128; off > 0; off >>= 1) {
        if (threadIdx.x < off) red[threadIdx.x] = fmaxf(red[threadIdx.x], red[threadIdx.x + off]);
        __syncthreads();
    }
    float mm = red[0]; __syncthreads();

    float s = 0.f;
    #pragma unroll
    for (int j = 0; j < 8; ++j) { v[j] = __expf(v[j] - mm); s += v[j]; }
    red[threadIdx.x] = s; __syncthreads();
    for (int off = 128; off > 0; off >>= 1) {
        if (threadIdx.x < off) red[threadIdx.x] += red[threadIdx.x + off];
        __syncthreads();
    }
    float inv = 1.f / red[0];
    s16x8 o;
    #pragma unroll
    for (int j = 0; j < 8; ++j) o[j] = (short)f2bf_rne(v[j] * inv);
    p[threadIdx.x] = o;
}

// In-place square transpose of (nb, Ln, Ln) bf16, 32x32 tile pairs.
__global__ __launch_bounds__(256)
void transpose_ip(unsigned short* __restrict__ G)
{
    int bi = blockIdx.y, bj = blockIdx.x;
    if (bj < bi) return;
    long base = (long)blockIdx.z * LLm;
    __shared__ unsigned short t1[32][33], t2[32][33];
    int tx = threadIdx.x & 31, ty = threadIdx.x >> 5;
    int r0 = bi * 32, c0 = bj * 32;
    #pragma unroll
    for (int i = 0; i < 4; ++i)
        t1[ty + 8 * i][tx] = G[base + (long)(r0 + ty + 8 * i) * Ln + c0 + tx];
    if (bi != bj) {
        #pragma unroll
        for (int i = 0; i < 4; ++i)
            t2[ty + 8 * i][tx] = G[base + (long)(c0 + ty + 8 * i) * Ln + r0 + tx];
    }
    __syncthreads();
    #pragma unroll
    for (int i = 0; i < 4; ++i)
        G[base + (long)(c0 + ty + 8 * i) * Ln + r0 + tx] = t1[tx][ty + 8 * i];
    if (bi != bj) {
        #pragma unroll
        for (int i = 0; i < 4; ++i)
            G[base + (long)(r0 + ty + 8 * i) * Ln + c0 + tx] = t2[tx][ty + 8 * i];
    }
}

// ---------------------------------------------------------------------------
// Host-side GEMM dispatch
// ---------------------------------------------------------------------------
static void glaunch(hipStream_t st, int epi,
                    const bf* A, long sAb, int ldA,
                    const bf* Bt, long sBb, int ldB,
                    void* C, long sCb, int ldC,
                    const float* bias, const float* rowN, const float* colN,
                    const float* resid, long sRb,
                    int M, int N, int K, int nb)
{
    dim3 g(N / 128, M / 128, nb), blk(256);
    const short* As = (const short*)A;
    const short* Bs = (const short*)Bt;
    switch (epi) {
    case EPI_BIAS:    gemm_nt<EPI_BIAS>   <<<g, blk, 0, st>>>(As, sAb, ldA, Bs, sBb, ldB, C, sCb, ldC, bias, rowN, colN, resid, sRb, M, N, K); break;
    case EPI_BIASM:   gemm_nt<EPI_BIASM>  <<<g, blk, 0, st>>>(As, sAb, ldA, Bs, sBb, ldB, C, sCb, ldC, bias, rowN, colN, resid, sRb, M, N, K); break;
    case EPI_PLAIN:   gemm_nt<EPI_PLAIN>  <<<g, blk, 0, st>>>(As, sAb, ldA, Bs, sBb, ldB, C, sCb, ldC, bias, rowN, colN, resid, sRb, M, N, K); break;
    case EPI_CAUCHY:  gemm_nt<EPI_CAUCHY> <<<g, blk, 0, st>>>(As, sAb, ldA, Bs, sBb, ldB, C, sCb, ldC, bias, rowN, colN, resid, sRb, M, N, K); break;
    case EPI_CAUCHYB: gemm_nt<EPI_CAUCHYB><<<g, blk, 0, st>>>(As, sAb, ldA, Bs, sBb, ldB, C, sCb, ldC, bias, rowN, colN, resid, sRb, M, N, K); break;
    default:          gemm_nt<EPI_RESID>  <<<g, blk, 0, st>>>(As, sAb, ldA, Bs, sBb, ldB, C, sCb, ldC, bias, rowN, colN, resid, sRb, M, N, K); break;
    }
}

extern "C" void kernel_launch(void* const* d_in, const int* in_sizes, int n_in,
                              void* d_out, int out_size, void* d_ws, size_t ws_size,
                              hipStream_t stream)
{
    const float* x = (const float*)d_in[0];
    float* out = (float*)d_out;

    // Arena (bytes), total 159,600,640:
    //   x_t   [0,          33,554,432)  (B,L,D) bf16; token phase: Gl half (4 x L x L bf16)
    //   dscore[33,554,432, 50,331,648)  (B,D,D) bf16
    //   Weff  [50,331,648, 58,720,256)  4 x (D,D) bf16
    //   beff  [58,720,256, +16K) b01_4 [+16K, +32K) norms [58,752,  ...]
    //   O1    [58,937,344, 126,046,208) 67MB: compose staging / dsdc concat / dscoreT / lslc concat
    //   O2    [126,046,208,159,600,640) 33.5MB: GdT fp32 / t1 bf16
    uint8_t* wsb = (uint8_t*)d_ws;
    if (ws_size < 159600640u) return;

    bf*    x_t    = (bf*)(wsb + 0);
    bf*    dscore = (bf*)(wsb + 33554432);
    bf*    Weff   = (bf*)(wsb + 50331648);
    float* beff   = (float*)(wsb + 58720256);    // 4 x D
    float* b01_4  = (float*)(wsb + 58736640);    // 4 x D
    float* ns_d   = (float*)(wsb + 58753024);
    float* nc_d   = ns_d + (long)Bn * Dn;
    float* ns_l   = nc_d + (long)Bn * Dn;
    float* nc_l   = ns_l + (long)Bn * Ln;
    uint8_t* O1   = wsb + 58937344;              // 67,108,864
    uint8_t* O2   = wsb + 126046208;             // 33,554,432

    // O1 sub-layouts (time-disjoint)
    bf* W1b4 = (bf*)O1;                // compose staging: 5 x 4*DDm shorts = 40MB
    bf* W2b4 = W1b4 + 4 * DDm;
    bf* W0t4 = W1b4 + 8 * DDm;
    bf* Zb4  = W1b4 + 12 * DDm;
    bf* Zt4  = W1b4 + 16 * DDm;
    bf* dsdc = (bf*)O1;                // (B, 2D, L) bf16 = 67MB
    bf* dscoreT = (bf*)O1;             // (B, D, D) bf16 (after dsdc dead)
    bf* lslc = (bf*)O1;                // (B, L, 2D) bf16 = 67MB

    float* GdT = (float*)O2;           // (B, D, D) fp32
    bf*    t1  = (bf*)O2;              // (B, D, L) bf16 (after GdT dead)
    bf*    Gl  = x_t;                  // token phase: 4 x (L, L) bf16 (x_t dead)

    P4 W, Bv;
    for (int k = 0; k < 4; ++k) { W.p[k] = (const float*)d_in[1 + 2 * k]; Bv.p[k] = (const float*)d_in[2 + 2 * k]; }

    // ---- x transpose-cast: (B,D,L) f32 -> (B,L,D) bf16 ----
    transpose_cast<float><<<dim3(Ln / 32, Dn / 32, Bn), 256, 0, stream>>>(x, x_t, Dn, Ln);

    // ---- weight staging (batched) + bias compose ----
    cast_w12<<<dim3((unsigned)(DDm / 4 / 256), 2, 4), 256, 0, stream>>>(W, W1b4, W2b4);
    transpose_w0<<<dim3(Dn / 32, Dn / 32, 4), 256, 0, stream>>>(W, W0t4);
    matvec4<<<dim3(Dn, 4), 256, 0, stream>>>(W, Bv, nullptr, b01_4, 0);
    matvec4<<<dim3(Dn, 4), 256, 0, stream>>>(W, Bv, b01_4, beff, 1);

    // ---- compose Weff = W2*W1*W0 (nb=4 batched) ----
    glaunch(stream, EPI_PLAIN, W1b4, DDm, Dn, W0t4, DDm, Dn, Zb4, DDm, Dn,
            nullptr, nullptr, nullptr, nullptr, 0, Dn, Dn, Dn, 4);
    transpose_cast<bf><<<dim3(Dn / 32, Dn / 32, 4), 256, 0, stream>>>(Zb4, Zt4, Dn, Dn);
    glaunch(stream, EPI_PLAIN, W2b4, DDm, Dn, Zt4, DDm, Dn, Weff, DDm, Dn,
            nullptr, nullptr, nullptr, nullptr, 0, Dn, Dn, Dn, 4);

    // ---- channel branch: dsx||dcx in one concat GEMM (M=2048, 2048 blocks) ----
    glaunch(stream, EPI_BIASM, Weff, 0, Dn, x_t, DL, Dn, dsdc, 2 * DL, Ln,
            beff, nullptr, nullptr, nullptr, 0, 2 * Dn, Ln, Dn, Bn);

    rowsumsq_s<<<dim3(Bn * Dn), 256, 0, stream>>>((const unsigned short*)dsdc,      ns_d, Ln, Ln, Dn, 2 * DL);
    rowsumsq_s<<<dim3(Bn * Dn), 256, 0, stream>>>((const unsigned short*)(dsdc + DL), nc_d, Ln, Ln, Dn, 2 * DL);

    // GdT fp32 = cauchy(dcx @ dsx^T) (rowN/colN swapped for the transpose)
    glaunch(stream, EPI_CAUCHY, dsdc + DL, 2 * DL, Ln, dsdc, 2 * DL, Ln, GdT, DDm, Dn,
            nullptr, nc_d, ns_d, nullptr, 0, Dn, Dn, Ln, Bn);
    // softmax over original axis 1 == row softmax of GdT -> dscoreT, then transpose
    softmax_row_bf16<Dn><<<dim3(Bn * Dn), 256, 0, stream>>>(GdT, dscoreT);
    transpose_cast<bf><<<dim3(Dn / 32, Dn / 32, Bn), 256, 0, stream>>>(dscoreT, dscore, Dn, Dn);

    // ---- token branch: lsx_t||lcx_t in one concat GEMM (N=2048, 2048 blocks) ----
    glaunch(stream, EPI_BIAS, x_t, DL, Dn, Weff + 2 * DDm, 0, Dn, lslc, 2 * DL, 2 * Dn,
            beff + 2 * Dn, nullptr, nullptr, nullptr, 0, Ln, 2 * Dn, Dn, Bn);

    rowsumsq_s<<<dim3(Bn * Ln), 256, 0, stream>>>((const unsigned short*)lslc,        ns_l, Dn, 2 * Dn, Ln, 2 * DL);
    rowsumsq_s<<<dim3(Bn * Ln), 256, 0, stream>>>((const unsigned short*)(lslc + Dn), nc_l, Dn, 2 * Dn, Ln, 2 * DL);

    // t1 = dscore @ x, all 8 batches (x_t and dscore dead afterwards)
    glaunch(stream, EPI_PLAIN, dscore, DDm, Dn, x_t, DL, Dn, t1, DL, Ln,
            nullptr, nullptr, nullptr, nullptr, 0, Dn, Ln, Dn, Bn);

    // ---- token score + apply, in 4-batch halves ----
    for (int h = 0; h < 2; ++h) {
        long bo = 4L * h;
        const bf* lsx = lslc + bo * 2 * DL;
        const bf* lcx = lsx + Dn;
        // Gl half bf16 = cauchy(lsx^T @ lcx) (normal layout), 1024 blocks
        glaunch(stream, EPI_CAUCHYB, lsx, 2 * DL, 2 * Dn, lcx, 2 * DL, 2 * Dn,
                Gl, LLm, Ln, nullptr, ns_l + bo * Ln, nc_l + bo * Ln, nullptr, 0,
                Ln, Ln, Dn, 4);
        // softmax over axis 2 == row softmax, in place
        softmax_ip_bf16<<<dim3(4 * Ln), 256, 0, stream>>>((unsigned short*)Gl);
        // in-place transpose -> lscore^T (Bt operand)
        transpose_ip<<<dim3(Ln / 32, Ln / 32, 4), 256, 0, stream>>>((unsigned short*)Gl);
        // out = (t1 @ lscore + x) / 2, 512 blocks
        glaunch(stream, EPI_RESID, t1 + bo * DL, DL, Ln, Gl, LLm, Ln,
                out + bo * DL, DL, Ln, nullptr, nullptr, nullptr, x + bo * DL, DL,
                Dn, Ln, Ln, 4);
    }
}